// Round 1
// baseline (21617.535 us; speedup 1.0000x reference)
//
#include <hip/hip_runtime.h>
#include <math.h>

#define T_STEPS 512
#define BATCH   64
#define IDIM    512
#define DDIM    1024
#define KTOT    (DDIM + IDIM)   // 1536
#define KC      128
#define NPHASE  (KTOT / KC)     // 12
#define HPHASE  (DDIM / KC)     // 8

// ---------------------------------------------------------------------------
// One-time: transpose state_below [T][B][I] -> sbT [T][I][B]
// ---------------------------------------------------------------------------
__global__ __launch_bounds__(256) void k_transpose_sb(const float* __restrict__ sb,
                                                      float* __restrict__ sbT) {
    __shared__ float tile[64][65];
    int bid = blockIdx.x;
    int t  = bid >> 3;          // /8 tiles per t  (I/64 = 8)
    int i0 = (bid & 7) << 6;
    const float* src = sb + (size_t)t * BATCH * IDIM;
    int tid = threadIdx.x;
    int row = tid >> 4;         // 0..15
    int c4  = (tid & 15) << 2;  // 0..60
#pragma unroll
    for (int rep = 0; rep < 4; ++rep) {
        int b = row + rep * 16;
        float4 v = *reinterpret_cast<const float4*>(src + (size_t)b * IDIM + i0 + c4);
        tile[b][c4 + 0] = v.x; tile[b][c4 + 1] = v.y;
        tile[b][c4 + 2] = v.z; tile[b][c4 + 3] = v.w;
    }
    __syncthreads();
    float* dst = sbT + ((size_t)t * IDIM + i0) * BATCH;
#pragma unroll
    for (int rep = 0; rep < 4; ++rep) {
        int ii = row + rep * 16;
        float4 v;
        v.x = tile[c4 + 0][ii]; v.y = tile[c4 + 1][ii];
        v.z = tile[c4 + 2][ii]; v.w = tile[c4 + 3][ii];
        *reinterpret_cast<float4*>(dst + (size_t)ii * BATCH + c4) = v;
    }
}

// ---------------------------------------------------------------------------
// One-time: build Wt[3][DDIM][KTOT]
//   g=0: col d of [U;W]      (r gate)
//   g=1: col D+d of [U;W]    (u gate)
//   g=2: col d of [Ux;Wx]    (candidate)
// rows k<1024 come from U/Ux (recurrent), k>=1024 from W/Wx (input)
// ---------------------------------------------------------------------------
__global__ __launch_bounds__(256) void k_build_wt(const float* __restrict__ U,
                                                  const float* __restrict__ Ux,
                                                  const float* __restrict__ W,
                                                  const float* __restrict__ Wx,
                                                  float* __restrict__ Wt) {
    __shared__ float tile[64][65];
    int bid = blockIdx.x;
    int g  = bid / (16 * 24);
    int r  = bid % (16 * 24);
    int dt = r / 24;
    int kt = r % 24;
    int d0 = dt << 6;
    int k0 = kt << 6;
    int tid = threadIdx.x;
    int row = tid >> 4;
    int c4  = (tid & 15) << 2;
#pragma unroll
    for (int rep = 0; rep < 4; ++rep) {
        int kk = row + rep * 16;
        int k = k0 + kk;
        const float* srcrow;
        if (k < DDIM) {
            srcrow = (g == 2) ? (Ux + (size_t)k * DDIM)
                              : (U + (size_t)k * (2 * DDIM) + (g == 1 ? DDIM : 0));
        } else {
            int kp = k - DDIM;
            srcrow = (g == 2) ? (Wx + (size_t)kp * DDIM)
                              : (W + (size_t)kp * (2 * DDIM) + (g == 1 ? DDIM : 0));
        }
        float4 v = *reinterpret_cast<const float4*>(srcrow + d0 + c4);
        tile[kk][c4 + 0] = v.x; tile[kk][c4 + 1] = v.y;
        tile[kk][c4 + 2] = v.z; tile[kk][c4 + 3] = v.w;
    }
    __syncthreads();
    float* dst = Wt + ((size_t)g * DDIM + d0) * KTOT + k0;
#pragma unroll
    for (int rep = 0; rep < 4; ++rep) {
        int dd = row + rep * 16;
        float4 v;
        v.x = tile[c4 + 0][dd]; v.y = tile[c4 + 1][dd];
        v.z = tile[c4 + 2][dd]; v.w = tile[c4 + 3][dd];
        *reinterpret_cast<float4*>(dst + (size_t)dd * KTOT + c4) = v;
    }
}

// ---------------------------------------------------------------------------
// Per-timestep fused kernel.
// grid = 256 blocks (4 d's each), 256 threads = 4 waves; wave wid owns
// d = bid*4 + wid, lane = batch index b.
// Computes for its d, all 64 b:
//   pre_r = [h;x]·Wt[0][d] ,  pre_u = [h;x]·Wt[1][d]
//   hu    = h·Ux[:,d]      ,  xxv   = x·Wx[:,d]          (kept separate!)
//   r=sig(pre_r+bW[d]) u=sig(pre_u+bW[D+d])
//   hc=tanh(hu*r + xxv + bWx[d]); hnew = u*h + (1-u)*hc; mask blend.
// ---------------------------------------------------------------------------
__global__ __launch_bounds__(256) void k_step(const float* __restrict__ Wt,
                                              const float* __restrict__ hT_prev, // [D][B]
                                              float* __restrict__ hT_next,       // [D][B]
                                              const float* __restrict__ sbT_t,   // [I][B]
                                              float* __restrict__ out_t,         // [B][D]
                                              const float* __restrict__ bW,
                                              const float* __restrict__ bWx,
                                              const float* __restrict__ mask_t,
                                              int first) {
    __shared__ float lds[KC * 65];
    __shared__ float ob[64 * 5];

    int tid  = threadIdx.x;
    int lane = tid & 63;
    int wid  = tid >> 6;
    int bidx = blockIdx.x;
    int d    = (bidx << 2) + wid;
    int du   = __builtin_amdgcn_readfirstlane(d);

    const float* w0p = Wt + (size_t)du * KTOT;
    const float* w1p = Wt + ((size_t)DDIM + du) * KTOT;
    const float* w2p = Wt + ((size_t)2 * DDIM + du) * KTOT;

    float accR0 = 0.f, accR1 = 0.f;
    float accU0 = 0.f, accU1 = 0.f;
    float accH0 = 0.f, accH1 = 0.f;
    float accX0 = 0.f, accX1 = 0.f;

    int pstart = first ? HPHASE : 0;
    for (int p = pstart; p < NPHASE; ++p) {
        int k0 = p * KC;
        const float* src = (p < HPHASE)
                               ? (hT_prev + (size_t)k0 * BATCH)
                               : (sbT_t + (size_t)(k0 - DDIM) * BATCH);
        __syncthreads();
        // stage KC x 64 floats -> lds[k][b] with row pad 65 (conflict-free)
        const float4* s4 = reinterpret_cast<const float4*>(src);
#pragma unroll
        for (int it = 0; it < (KC * 16) / 256; ++it) {
            int j  = tid + it * 256;
            float4 v = s4[j];
            int kk = j >> 4;
            int c4 = (j & 15) << 2;
            float* dl = &lds[kk * 65 + c4];
            dl[0] = v.x; dl[1] = v.y; dl[2] = v.z; dl[3] = v.w;
        }
        __syncthreads();

        if (p < HPHASE) {
#pragma unroll 8
            for (int k = 0; k < KC; k += 2) {
                float v0 = lds[k * 65 + lane];
                float v1 = lds[(k + 1) * 65 + lane];
                accR0 += v0 * w0p[k0 + k];     accR1 += v1 * w0p[k0 + k + 1];
                accU0 += v0 * w1p[k0 + k];     accU1 += v1 * w1p[k0 + k + 1];
                accH0 += v0 * w2p[k0 + k];     accH1 += v1 * w2p[k0 + k + 1];
            }
        } else {
#pragma unroll 8
            for (int k = 0; k < KC; k += 2) {
                float v0 = lds[k * 65 + lane];
                float v1 = lds[(k + 1) * 65 + lane];
                accR0 += v0 * w0p[k0 + k];     accR1 += v1 * w0p[k0 + k + 1];
                accU0 += v0 * w1p[k0 + k];     accU1 += v1 * w1p[k0 + k + 1];
                accX0 += v0 * w2p[k0 + k];     accX1 += v1 * w2p[k0 + k + 1];
            }
        }
    }

    float pre_r = accR0 + accR1 + bW[du];
    float pre_u = accU0 + accU1 + bW[DDIM + du];
    float hu    = accH0 + accH1;
    float xxv   = accX0 + accX1 + bWx[du];

    float hOld = first ? 0.f : hT_prev[(size_t)du * BATCH + lane];
    float m    = mask_t[lane];

    float r  = 1.f / (1.f + expf(-pre_r));
    float u  = 1.f / (1.f + expf(-pre_u));
    float hc = tanhf(hu * r + xxv);
    float hnew = u * hOld + (1.f - u) * hc;
    hnew = m * hnew + (1.f - m) * hOld;

    hT_next[(size_t)du * BATCH + lane] = hnew;
    ob[lane * 5 + wid] = hnew;
    __syncthreads();
    if (wid == 0) {
        float4 v;
        v.x = ob[lane * 5 + 0]; v.y = ob[lane * 5 + 1];
        v.z = ob[lane * 5 + 2]; v.w = ob[lane * 5 + 3];
        *reinterpret_cast<float4*>(out_t + (size_t)lane * DDIM + (bidx << 2)) = v;
    }
}

// ---------------------------------------------------------------------------
extern "C" void kernel_launch(void* const* d_in, const int* in_sizes, int n_in,
                              void* d_out, int out_size, void* d_ws, size_t ws_size,
                              hipStream_t stream) {
    const float* sb   = (const float*)d_in[0];
    const float* mask = (const float*)d_in[1];
    const float* W    = (const float*)d_in[2];
    const float* bW   = (const float*)d_in[3];
    const float* Wx   = (const float*)d_in[4];
    const float* bWx  = (const float*)d_in[5];
    const float* U    = (const float*)d_in[6];
    const float* Ux   = (const float*)d_in[7];
    float* out = (float*)d_out;
    float* ws  = (float*)d_ws;

    float* Wt  = ws;                                    // 3*1024*1536  = 4,718,592 f
    float* sbT = Wt + (size_t)3 * DDIM * KTOT;          // 512*512*64   = 16,777,216 f
    float* hT  = sbT + (size_t)T_STEPS * IDIM * BATCH;  // 2*1024*64    = 131,072 f
                                                        // total ~86.5 MB

    k_build_wt<<<dim3(3 * 16 * 24), 256, 0, stream>>>(U, Ux, W, Wx, Wt);
    k_transpose_sb<<<dim3(T_STEPS * (IDIM / 64)), 256, 0, stream>>>(sb, sbT);

    for (int t = 0; t < T_STEPS; ++t) {
        float* hprev = hT + (size_t)(t & 1) * DDIM * BATCH;
        float* hnext = hT + (size_t)((t + 1) & 1) * DDIM * BATCH;
        k_step<<<dim3(DDIM / 4), 256, 0, stream>>>(
            Wt, hprev, hnext,
            sbT + (size_t)t * IDIM * BATCH,
            out + (size_t)t * BATCH * DDIM,
            bW, bWx,
            mask + (size_t)t * BATCH,
            t == 0 ? 1 : 0);
    }
}